// Round 7
// baseline (363.237 us; speedup 1.0000x reference)
//
#include <hip/hip_runtime.h>
#include <cstdint>
#include <cstddef>

typedef float f32x4 __attribute__((ext_vector_type(4)));
typedef __bf16 bf16x8 __attribute__((ext_vector_type(8)));

__device__ __forceinline__ float b2f(unsigned short u) {
    union { unsigned int i; float f; } z; z.i = ((unsigned int)u) << 16; return z.f;
}
__device__ __forceinline__ unsigned short f2b(float f) {
    union { float f; unsigned int i; } z; z.f = f;
    unsigned int x = z.i;
    return (unsigned short)((x + 0x7FFFu + ((x >> 16) & 1u)) >> 16);
}

static constexpr int C = 128;
static constexpr int NP = 16384;      // H*W
static constexpr int NH = 8;

// ---------- weight pack: fp32 -> bf16; dwconv weights transposed to [9][CH] ----------
struct Ptr11 { const float* p[11]; };
__constant__ int kWN[11]    = {128, 128, 8, 49152, 3456, 16384, 128, 128, 65536, 4608, 32768};
__constant__ int kWOff[11]  = {0, 128, 256, 272, 49424, 52880, 69264, 69392, 69520, 135056, 139664};
__constant__ int kWTr[11]   = {0, 0, 0, 0, 384, 0, 0, 0, 0, 512, 0};   // CH if transpose [c][9]->[9][CH]
static constexpr int kWTotal = 172432;

__global__ __launch_bounds__(256)
void cvt_w_kernel(Ptr11 P, unsigned short* __restrict__ dst)
{
    int seg = blockIdx.y;
    int n = kWN[seg];
    int i = blockIdx.x * 256 + threadIdx.x;
    if (i >= n) return;
    unsigned short v = f2b(P.p[seg][i]);
    int tr = kWTr[seg];
    if (tr) { int c = i / 9, t = i % 9; dst[kWOff[seg] + t * tr + c] = v; }
    else dst[kWOff[seg] + i] = v;
}

// ---------- zero norms2 ----------
__global__ void zero_kernel(float* __restrict__ p) { p[blockIdx.x * 256 + threadIdx.x] = 0.f; }

// ---------- LayerNorm: fp32 [c][n] in -> bf16 [n][c] out ----------
// block: 16 px x 16 c-octets
__global__ __launch_bounds__(256)
void ln_kernel(const float* __restrict__ x, const unsigned short* __restrict__ g,
               const unsigned short* __restrict__ beta, unsigned short* __restrict__ y)
{
    int t = threadIdx.x;
    int px = t & 15;
    int tg = t >> 4;
    int pglob = blockIdx.x * 16 + px;      // b*NP+n
    int b = pglob >> 14;
    int n = pglob & (NP - 1);
    const float* xb = x + (size_t)b * C * NP + n;

    float v[8]; float s = 0.f, s2 = 0.f;
    #pragma unroll
    for (int i = 0; i < 8; ++i) {
        float w = xb[(size_t)(tg * 8 + i) * NP];
        v[i] = w; s += w; s2 += w * w;
    }
    s  += __shfl_xor(s, 16, 64);  s2 += __shfl_xor(s2, 16, 64);
    s  += __shfl_xor(s, 32, 64);  s2 += __shfl_xor(s2, 32, 64);
    __shared__ float sm[2][4][16];
    if ((t & 63) < 16) { sm[0][t >> 6][px] = s; sm[1][t >> 6][px] = s2; }
    __syncthreads();
    float S  = sm[0][0][px] + sm[0][1][px] + sm[0][2][px] + sm[0][3][px];
    float S2 = sm[1][0][px] + sm[1][1][px] + sm[1][2][px] + sm[1][3][px];
    float mu = S * (1.0f / C);
    float var = S2 * (1.0f / C) - mu * mu;
    float rs = rsqrtf(fmaxf(var, 0.f) + 1e-5f);

    union { uint4 q; unsigned short u[8]; } res;
    #pragma unroll
    for (int i = 0; i < 8; ++i) {
        int c = tg * 8 + i;
        res.u[i] = f2b((v[i] - mu) * rs * b2f(g[c]) + b2f(beta[c]));
    }
    *(uint4*)(y + (size_t)pglob * C + tg * 8) = res.q;
}

// ---------- 1x1 conv GEMM, LDS-free: X'[n][k] (A), W[co][k] (B) ----------
// EPI 0: Out bf16 [n][co]. EPI 1: Out fp32 [co][n] = Res[co][n] + acc.
template <int K, int EPI>
__global__ __launch_bounds__(256)
void gemm_pconv(const unsigned short* __restrict__ W,
                const unsigned short* __restrict__ X,
                void* __restrict__ Out,
                const float* __restrict__ Res,
                int Cout)
{
    const int tid = threadIdx.x;
    const int b = blockIdx.z;
    const int n0 = blockIdx.x * 128;
    const int co0 = blockIdx.y * 128;
    const int lane = tid & 63;
    const int wid = tid >> 6;
    const int ln16 = lane & 15;
    const int quad = lane >> 4;
    const int wy = wid >> 1;     // n half
    const int wx = wid & 1;      // co half
    const unsigned short* Xb = X + ((size_t)b * NP + n0) * K;

    f32x4 acc[4][4];
    #pragma unroll
    for (int i = 0; i < 4; ++i)
        #pragma unroll
        for (int j = 0; j < 4; ++j)
            acc[i][j] = f32x4{0.f, 0.f, 0.f, 0.f};

    #pragma unroll 2
    for (int k0 = 0; k0 < K; k0 += 32) {
        bf16x8 afr[4];
        #pragma unroll
        for (int mt = 0; mt < 4; ++mt) {
            int row = wy * 64 + mt * 16 + ln16;
            uint4 v = *(const uint4*)(Xb + (size_t)row * K + k0 + quad * 8);
            afr[mt] = *(bf16x8*)&v;
        }
        bf16x8 bfr[4];
        #pragma unroll
        for (int nt = 0; nt < 4; ++nt) {
            int co = co0 + wx * 64 + nt * 16 + ln16;
            uint4 v = *(const uint4*)(W + (size_t)co * K + k0 + quad * 8);
            bfr[nt] = *(bf16x8*)&v;
        }
        #pragma unroll
        for (int mt = 0; mt < 4; ++mt)
            #pragma unroll
            for (int nt = 0; nt < 4; ++nt)
                acc[mt][nt] = __builtin_amdgcn_mfma_f32_16x16x32_bf16(
                    afr[mt], bfr[nt], acc[mt][nt], 0, 0, 0);
    }

    // D: row (=pixel) = quad*4+r, col (=co) = ln16
    #pragma unroll
    for (int mt = 0; mt < 4; ++mt) {
        #pragma unroll
        for (int nt = 0; nt < 4; ++nt) {
            int co = co0 + wx * 64 + nt * 16 + ln16;
            #pragma unroll
            for (int r = 0; r < 4; ++r) {
                int n = n0 + wy * 64 + mt * 16 + quad * 4 + r;
                float v = acc[mt][nt][r];
                if (EPI == 0) {
                    ((unsigned short*)Out)[((size_t)b * NP + n) * Cout + co] = f2b(v);
                } else {
                    size_t idx = (size_t)b * Cout * NP + (size_t)co * NP + n;
                    ((float*)Out)[idx] = Res[idx] + v;
                }
            }
        }
    }
}

// ---------- depthwise 3x3 in [n][c]: 8 channels per thread ----------
template <int CH>
__global__ __launch_bounds__(256)
void dwconv3_kernel(const unsigned short* __restrict__ in,
                    const unsigned short* __restrict__ w9t,   // [9][CH]
                    unsigned short* __restrict__ out)
{
    constexpr int CHD = CH / 8;
    int gid = blockIdx.x * 256 + threadIdx.x;
    int c8 = gid % CHD;
    int rest = gid / CHD;
    int n = rest & (NP - 1);
    int b = rest >> 14;
    int x0 = n & 127, y0 = n >> 7;
    const unsigned short* base = in + ((size_t)b * NP + n) * CH + c8 * 8;

    float acc[8];
    #pragma unroll
    for (int j = 0; j < 8; ++j) acc[j] = 0.f;

    #pragma unroll
    for (int dy = -1; dy <= 1; ++dy) {
        int yy = y0 + dy;
        if (yy < 0 || yy > 127) continue;
        #pragma unroll
        for (int dx = -1; dx <= 1; ++dx) {
            int xx = x0 + dx;
            if (xx < 0 || xx > 127) continue;
            union { uint4 q; unsigned short u[8]; } pv, wv;
            pv.q = *(const uint4*)(base + (ptrdiff_t)(dy * 128 + dx) * CH);
            wv.q = *(const uint4*)(w9t + ((dy + 1) * 3 + dx + 1) * CH + c8 * 8);
            #pragma unroll
            for (int j = 0; j < 8; ++j) acc[j] += b2f(pv.u[j]) * b2f(wv.u[j]);
        }
    }
    union { uint4 q; unsigned short u[8]; } res;
    #pragma unroll
    for (int j = 0; j < 8; ++j) res.u[j] = f2b(acc[j]);
    *(uint4*)(out + ((size_t)b * NP + n) * CH + c8 * 8) = res.q;
}

// ---------- fused dw3x3 + tanh-GELU gate in [n][c]: hdn'[n][512] -> g'[n][256] ----------
__global__ __launch_bounds__(256)
void dwgelu_kernel(const unsigned short* __restrict__ hdn,
                   const unsigned short* __restrict__ w9t,   // [9][512]
                   unsigned short* __restrict__ g)
{
    int gid = blockIdx.x * 256 + threadIdx.x;
    int c8 = gid & 31;
    int rest = gid >> 5;
    int n = rest & (NP - 1);
    int b = rest >> 14;
    int x0 = n & 127, y0 = n >> 7;
    const unsigned short* base = hdn + ((size_t)b * NP + n) * 512 + c8 * 8;

    float a1[8], a2[8];
    #pragma unroll
    for (int j = 0; j < 8; ++j) { a1[j] = 0.f; a2[j] = 0.f; }

    #pragma unroll
    for (int dy = -1; dy <= 1; ++dy) {
        int yy = y0 + dy;
        if (yy < 0 || yy > 127) continue;
        #pragma unroll
        for (int dx = -1; dx <= 1; ++dx) {
            int xx = x0 + dx;
            if (xx < 0 || xx > 127) continue;
            const unsigned short* p = base + (ptrdiff_t)(dy * 128 + dx) * 512;
            const unsigned short* w = w9t + ((dy + 1) * 3 + dx + 1) * 512 + c8 * 8;
            union { uint4 q; unsigned short u[8]; } p1, p2, w1, w2;
            p1.q = *(const uint4*)p;
            p2.q = *(const uint4*)(p + 256);
            w1.q = *(const uint4*)w;
            w2.q = *(const uint4*)(w + 256);
            #pragma unroll
            for (int j = 0; j < 8; ++j) {
                a1[j] += b2f(p1.u[j]) * b2f(w1.u[j]);
                a2[j] += b2f(p2.u[j]) * b2f(w2.u[j]);
            }
        }
    }
    union { uint4 q; unsigned short u[8]; } res;
    #pragma unroll
    for (int j = 0; j < 8; ++j) {
        float u = a1[j];
        float tt = u * (0.7978845608f + 0.0356774081f * u * u);
        float e = __expf(2.f * tt);
        float th = 1.f - 2.f / (e + 1.f);
        res.u[j] = f2b(0.5f * u * (1.f + th) * a2[j]);
    }
    *(uint4*)(g + ((size_t)b * NP + n) * 256 + c8 * 8) = res.q;
}

// ---------- sum of squares per (b, ch<256) over n; atomic accumulate ----------
__global__ __launch_bounds__(256)
void sumsq_kernel(const unsigned short* __restrict__ qkv, float* __restrict__ norms2)
{
    int t = threadIdx.x;
    int c8 = t & 31, npar = t >> 5;
    int b = blockIdx.y;
    int nbase = blockIdx.x * 64 + npar * 8;
    float ps[8];
    #pragma unroll
    for (int j = 0; j < 8; ++j) ps[j] = 0.f;
    for (int i = 0; i < 8; ++i) {
        int n = nbase + i;
        union { uint4 q; unsigned short u[8]; } cv;
        cv.q = *(const uint4*)(qkv + ((size_t)b * NP + n) * 384 + c8 * 8);
        #pragma unroll
        for (int j = 0; j < 8; ++j) { float v = b2f(cv.u[j]); ps[j] += v * v; }
    }
    __shared__ float sm[8][256];
    #pragma unroll
    for (int j = 0; j < 8; ++j) sm[npar][c8 * 8 + j] = ps[j];
    __syncthreads();
    float s = 0.f;
    #pragma unroll
    for (int k = 0; k < 8; ++k) s += sm[k][t];
    atomicAdd(&norms2[b * 256 + t], s);
}

// ---------- Gram partials with in-LDS transpose: Spart[b,h,slot(32)][dq][dk] ----------
__global__ __launch_bounds__(256)
void gram_kernel(const unsigned short* __restrict__ qkv, float* __restrict__ Spart)
{
    __shared__ unsigned short Qs[16][136], Ks[16][136];
    int h = blockIdx.x, b = blockIdx.y, sp = blockIdx.z;   // sp 0..7, 2048 n each
    int t = threadIdx.x;
    int wave = t >> 6, lane = t & 63;
    int ln16 = lane & 15, quad = lane >> 4;
    int half = t & 1, nl = t >> 1;                         // 128 rows x 2 halves

    f32x4 acc = f32x4{0.f, 0.f, 0.f, 0.f};
    for (int sub = 0; sub < 16; ++sub) {
        const unsigned short* row = qkv + ((size_t)b * NP + sp * 2048 + sub * 128 + nl) * 384 + h * 16 + half * 8;
        uint4 qv = *(const uint4*)row;
        uint4 kv = *(const uint4*)(row + 128);
        __syncthreads();
        union { uint4 q; unsigned short u[8]; } qq, kk;
        qq.q = qv; kk.q = kv;
        #pragma unroll
        for (int j = 0; j < 8; ++j) {
            Qs[half * 8 + j][nl] = qq.u[j];
            Ks[half * 8 + j][nl] = kk.u[j];
        }
        __syncthreads();
        bf16x8 aq = *(const bf16x8*)&Qs[ln16][wave * 32 + quad * 8];
        bf16x8 bk = *(const bf16x8*)&Ks[ln16][wave * 32 + quad * 8];
        acc = __builtin_amdgcn_mfma_f32_16x16x32_bf16(aq, bk, acc, 0, 0, 0);
    }
    float* Sp = Spart + (((size_t)(b * NH + h) * 32) + sp * 4 + wave) * 256;
    #pragma unroll
    for (int r = 0; r < 4; ++r)
        Sp[(quad * 4 + r) * 16 + ln16] = acc[r];
}

// ---------- softmax over dk ----------
__global__ __launch_bounds__(256)
void softmax_kernel(const float* __restrict__ Spart, const float* __restrict__ norms2,
                    const unsigned short* __restrict__ temp, float* __restrict__ P)
{
    int bh = blockIdx.x;
    int b = bh >> 3, h = bh & 7;
    int t = threadIdx.x;
    int dq = t >> 4, dk = t & 15;
    float sacc = 0.f;
    const float* Sp = Spart + (size_t)bh * 32 * 256;
    #pragma unroll
    for (int j = 0; j < 32; ++j) sacc += Sp[j * 256 + t];
    float nq = fmaxf(sqrtf(norms2[b * 256 + h * 16 + dq]), 1e-12f);
    float nk = fmaxf(sqrtf(norms2[b * 256 + 128 + h * 16 + dk]), 1e-12f);
    float v = sacc / (nq * nk) * b2f(temp[h]);
    float m = v;
    #pragma unroll
    for (int o = 8; o > 0; o >>= 1) m = fmaxf(m, __shfl_xor(m, o, 16));
    float e = __expf(v - m);
    float s = e;
    #pragma unroll
    for (int o = 8; o > 0; o >>= 1) s += __shfl_xor(s, o, 16);
    P[(size_t)bh * 256 + t] = e / s;
}

// ---------- attn-V in [n][c]: block = 32 n x 8 h ----------
__global__ __launch_bounds__(256)
void attnv_kernel(const float* __restrict__ P, const unsigned short* __restrict__ qkv,
                  unsigned short* __restrict__ out)
{
    __shared__ float Ps[8][260];
    int b = blockIdx.y;
    int t = threadIdx.x;
    const float* Pg = P + (size_t)b * NH * 256;
    #pragma unroll
    for (int i = 0; i < 8; ++i) {
        int idx = t + 256 * i;
        Ps[idx >> 8][idx & 255] = Pg[idx];
    }
    __syncthreads();
    int h = t & 7, nloc = t >> 3;
    int n = blockIdx.x * 32 + nloc;
    const unsigned short* vrow = qkv + ((size_t)b * NP + n) * 384 + 256 + h * 16;
    union { uint4 q; unsigned short u[8]; } v0, v1;
    v0.q = *(const uint4*)vrow;
    v1.q = *(const uint4*)(vrow + 8);
    float vv[16];
    #pragma unroll
    for (int j = 0; j < 8; ++j) { vv[j] = b2f(v0.u[j]); vv[8 + j] = b2f(v1.u[j]); }
    union { uint4 q[2]; unsigned short u[16]; } res;
    #pragma unroll
    for (int dq = 0; dq < 16; ++dq) {
        float o = 0.f;
        #pragma unroll
        for (int e4 = 0; e4 < 4; ++e4) {
            f32x4 p4 = *(const f32x4*)&Ps[h][dq * 16 + e4 * 4];
            o += p4[0] * vv[e4 * 4] + p4[1] * vv[e4 * 4 + 1] + p4[2] * vv[e4 * 4 + 2] + p4[3] * vv[e4 * 4 + 3];
        }
        res.u[dq] = f2b(o);
    }
    unsigned short* op = out + ((size_t)b * NP + n) * C + h * 16;
    *(uint4*)op = res.q[0];
    *(uint4*)(op + 8) = res.q[1];
}

// ---------- pipeline ----------
struct Bufs {
    float* xmid;            // [c][n] fp32 trunk
    unsigned short* y;      // [n][128] bf16
    unsigned short* big;    // [n][512] bf16
    unsigned short* mid;    // [n][384] / [n][256] bf16
    float* norms2;          // nb*256
    float* Spart;           // nb*NH*32*256
    float* P;               // nb*NH*256
};

static void run_pipeline(const float* x_f32, float* out_f32,
                         const unsigned short* w, const Bufs& B, int nb, hipStream_t stream)
{
    const unsigned short* ln1_w   = w + 0;
    const unsigned short* ln1_b   = w + 128;
    const unsigned short* temp    = w + 256;
    const unsigned short* qkv_p_w = w + 272;
    const unsigned short* qkv_d_w = w + 49424;    // [9][384]
    const unsigned short* proj_w  = w + 52880;
    const unsigned short* ln2_w   = w + 69264;
    const unsigned short* ln2_b   = w + 69392;
    const unsigned short* g1_w    = w + 69520;
    const unsigned short* gd_w    = w + 135056;   // [9][512]
    const unsigned short* g2_w    = w + 139664;

    // ---- MDTA ----
    ln_kernel<<<nb * NP / 16, 256, 0, stream>>>(x_f32, ln1_w, ln1_b, B.y);
    gemm_pconv<128, 0><<<dim3(NP / 128, 3, nb), 256, 0, stream>>>(qkv_p_w, B.y, B.big, nullptr, 384);
    dwconv3_kernel<384><<<nb * NP * 48 / 256, 256, 0, stream>>>(B.big, qkv_d_w, B.mid);
    zero_kernel<<<nb, 256, 0, stream>>>(B.norms2);
    sumsq_kernel<<<dim3(NP / 64, nb), 256, 0, stream>>>(B.mid, B.norms2);
    gram_kernel<<<dim3(NH, nb, 8), 256, 0, stream>>>(B.mid, B.Spart);
    softmax_kernel<<<nb * NH, 256, 0, stream>>>(B.Spart, B.norms2, temp, B.P);
    attnv_kernel<<<dim3(NP / 32, nb), 256, 0, stream>>>(B.P, B.mid, B.y);
    gemm_pconv<128, 1><<<dim3(NP / 128, 1, nb), 256, 0, stream>>>(proj_w, B.y, B.xmid, x_f32, 128);

    // ---- GDFN ----
    ln_kernel<<<nb * NP / 16, 256, 0, stream>>>(B.xmid, ln2_w, ln2_b, B.y);
    gemm_pconv<128, 0><<<dim3(NP / 128, 4, nb), 256, 0, stream>>>(g1_w, B.y, B.big, nullptr, 512);
    dwgelu_kernel<<<nb * NP * 32 / 256, 256, 0, stream>>>(B.big, gd_w, B.mid);
    gemm_pconv<256, 1><<<dim3(NP / 128, 1, nb), 256, 0, stream>>>(g2_w, B.mid, out_f32, B.xmid, 128);
}

extern "C" void kernel_launch(void* const* d_in, const int* in_sizes, int n_in,
                              void* d_out, int out_size, void* d_ws, size_t ws_size,
                              hipStream_t stream)
{
    (void)in_sizes; (void)n_in; (void)out_size;
    const float* x = (const float*)d_in[0];
    char* ws = (char*)d_ws;

    size_t off = 0;
    unsigned short* wpack = (unsigned short*)(ws + off);
    off += (size_t)kWTotal * 2;
    off = (off + 255) & ~(size_t)255;
    size_t header = off;

    auto layout = [&](int nb, size_t o, Bufs& B) -> size_t {
        B.xmid = (float*)(ws + o);           o += (size_t)nb * C * NP * 4;
        B.y    = (unsigned short*)(ws + o);  o += (size_t)nb * C * NP * 2;
        B.big  = (unsigned short*)(ws + o);  o += (size_t)nb * 512 * NP * 2;
        B.mid  = (unsigned short*)(ws + o);  o += (size_t)nb * 384 * NP * 2;
        B.norms2 = (float*)(ws + o);         o += (size_t)nb * 256 * 4;
        B.Spart  = (float*)(ws + o);         o += (size_t)nb * NH * 32 * 256 * 4;
        B.P      = (float*)(ws + o);         o += (size_t)nb * NH * 256 * 4;
        return o;
    };

    Ptr11 P;
    for (int i = 0; i < 11; ++i) P.p[i] = (const float*)d_in[i + 1];
    cvt_w_kernel<<<dim3(256, 11), 256, 0, stream>>>(P, wpack);

    Bufs Bfull;
    size_t need_full = layout(4, header, Bfull);

    if (ws_size >= need_full) {
        run_pipeline(x, (float*)d_out, wpack, Bfull, 4, stream);
    } else {
        Bufs B1;
        layout(1, header, B1);
        for (int b = 0; b < 4; ++b) {
            run_pipeline(x + (size_t)b * C * NP,
                         (float*)d_out + (size_t)b * C * NP,
                         wpack, B1, 1, stream);
        }
    }
}

// Round 8
// 355.895 us; speedup vs baseline: 1.0206x; 1.0206x over previous
//
#include <hip/hip_runtime.h>
#include <cstdint>
#include <cstddef>

typedef float f32x4 __attribute__((ext_vector_type(4)));
typedef __bf16 bf16x8 __attribute__((ext_vector_type(8)));

__device__ __forceinline__ float b2f(unsigned short u) {
    union { unsigned int i; float f; } z; z.i = ((unsigned int)u) << 16; return z.f;
}
__device__ __forceinline__ unsigned short f2b(float f) {
    union { float f; unsigned int i; } z; z.f = f;
    unsigned int x = z.i;
    return (unsigned short)((x + 0x7FFFu + ((x >> 16) & 1u)) >> 16);
}

static constexpr int C = 128;
static constexpr int NP = 16384;      // H*W
static constexpr int NH = 8;

// ---------- weight pack: fp32 -> bf16; dwconv weights transposed to [9][CH] ----------
struct Ptr11 { const float* p[11]; };
__constant__ int kWN[11]    = {128, 128, 8, 49152, 3456, 16384, 128, 128, 65536, 4608, 32768};
__constant__ int kWOff[11]  = {0, 128, 256, 272, 49424, 52880, 69264, 69392, 69520, 135056, 139664};
__constant__ int kWTr[11]   = {0, 0, 0, 0, 384, 0, 0, 0, 0, 512, 0};   // CH if transpose [c][9]->[9][CH]
static constexpr int kWTotal = 172432;

__global__ __launch_bounds__(256)
void cvt_w_kernel(Ptr11 P, unsigned short* __restrict__ dst)
{
    int seg = blockIdx.y;
    int n = kWN[seg];
    int i = blockIdx.x * 256 + threadIdx.x;
    if (i >= n) return;
    unsigned short v = f2b(P.p[seg][i]);
    int tr = kWTr[seg];
    if (tr) { int c = i / 9, t = i % 9; dst[kWOff[seg] + t * tr + c] = v; }
    else dst[kWOff[seg] + i] = v;
}

// ---------- zero norms2 ----------
__global__ void zero_kernel(float* __restrict__ p) { p[blockIdx.x * 256 + threadIdx.x] = 0.f; }

// ---------- LayerNorm: fp32 [c][n] in -> bf16 [n][c] out ----------
__global__ __launch_bounds__(256)
void ln_kernel(const float* __restrict__ x, const unsigned short* __restrict__ g,
               const unsigned short* __restrict__ beta, unsigned short* __restrict__ y)
{
    int t = threadIdx.x;
    int px = t & 15;
    int tg = t >> 4;
    int pglob = blockIdx.x * 16 + px;      // b*NP+n
    int b = pglob >> 14;
    int n = pglob & (NP - 1);
    const float* xb = x + (size_t)b * C * NP + n;

    float v[8]; float s = 0.f, s2 = 0.f;
    #pragma unroll
    for (int i = 0; i < 8; ++i) {
        float w = xb[(size_t)(tg * 8 + i) * NP];
        v[i] = w; s += w; s2 += w * w;
    }
    s  += __shfl_xor(s, 16, 64);  s2 += __shfl_xor(s2, 16, 64);
    s  += __shfl_xor(s, 32, 64);  s2 += __shfl_xor(s2, 32, 64);
    __shared__ float sm[2][4][16];
    if ((t & 63) < 16) { sm[0][t >> 6][px] = s; sm[1][t >> 6][px] = s2; }
    __syncthreads();
    float S  = sm[0][0][px] + sm[0][1][px] + sm[0][2][px] + sm[0][3][px];
    float S2 = sm[1][0][px] + sm[1][1][px] + sm[1][2][px] + sm[1][3][px];
    float mu = S * (1.0f / C);
    float var = S2 * (1.0f / C) - mu * mu;
    float rs = rsqrtf(fmaxf(var, 0.f) + 1e-5f);

    union { uint4 q; unsigned short u[8]; } res;
    #pragma unroll
    for (int i = 0; i < 8; ++i) {
        int c = tg * 8 + i;
        res.u[i] = f2b((v[i] - mu) * rs * b2f(g[c]) + b2f(beta[c]));
    }
    *(uint4*)(y + (size_t)pglob * C + tg * 8) = res.q;
}

// ---------- 1x1 conv GEMM, LDS-free K-loop: X'[n][k] (A), W[co][k] (B) ----------
// EPI 0: Out bf16 [n][co] via LDS-transpose, coalesced dwordx4 stores.
// EPI 1: Out fp32 [co][n] = Res[co][n] + acc, float4 RMW.
template <int K, int EPI>
__global__ __launch_bounds__(256)
void gemm_pconv(const unsigned short* __restrict__ W,
                const unsigned short* __restrict__ X,
                void* __restrict__ Out,
                const float* __restrict__ Res,
                int Cout)
{
    const int tid = threadIdx.x;
    const int b = blockIdx.z;
    const int n0 = blockIdx.x * 128;
    const int co0 = blockIdx.y * 128;
    const int lane = tid & 63;
    const int wid = tid >> 6;
    const int ln16 = lane & 15;
    const int quad = lane >> 4;
    const int wy = wid >> 1;     // n half
    const int wx = wid & 1;      // co half
    const unsigned short* Xb = X + ((size_t)b * NP + n0) * K;

    f32x4 acc[4][4];
    #pragma unroll
    for (int i = 0; i < 4; ++i)
        #pragma unroll
        for (int j = 0; j < 4; ++j)
            acc[i][j] = f32x4{0.f, 0.f, 0.f, 0.f};

    #pragma unroll 2
    for (int k0 = 0; k0 < K; k0 += 32) {
        bf16x8 afr[4];
        #pragma unroll
        for (int mt = 0; mt < 4; ++mt) {
            int row = wy * 64 + mt * 16 + ln16;
            uint4 v = *(const uint4*)(Xb + (size_t)row * K + k0 + quad * 8);
            afr[mt] = *(bf16x8*)&v;
        }
        bf16x8 bfr[4];
        #pragma unroll
        for (int nt = 0; nt < 4; ++nt) {
            int co = co0 + wx * 64 + nt * 16 + ln16;
            uint4 v = *(const uint4*)(W + (size_t)co * K + k0 + quad * 8);
            bfr[nt] = *(bf16x8*)&v;
        }
        #pragma unroll
        for (int mt = 0; mt < 4; ++mt)
            #pragma unroll
            for (int nt = 0; nt < 4; ++nt)
                acc[mt][nt] = __builtin_amdgcn_mfma_f32_16x16x32_bf16(
                    afr[mt], bfr[nt], acc[mt][nt], 0, 0, 0);
    }

    // D: row (=pixel within tile) = quad*4+r, col (=co) = ln16
    if constexpr (EPI == 0) {
        __shared__ unsigned short Ts[128 * 136];
        #pragma unroll
        for (int mt = 0; mt < 4; ++mt) {
            #pragma unroll
            for (int nt = 0; nt < 4; ++nt) {
                int col = wx * 64 + nt * 16 + ln16;
                int row0 = wy * 64 + mt * 16 + quad * 4;
                #pragma unroll
                for (int r = 0; r < 4; ++r)
                    Ts[(row0 + r) * 136 + col] = f2b(acc[mt][nt][r]);
            }
        }
        __syncthreads();
        unsigned short* ob = (unsigned short*)Out;
        #pragma unroll
        for (int i = 0; i < 8; ++i) {
            int idx = tid + 256 * i;      // 0..2047
            int n = idx >> 4;
            int oct = idx & 15;
            uint4 v = *(const uint4*)&Ts[n * 136 + oct * 8];
            *(uint4*)(ob + ((size_t)b * NP + n0 + n) * Cout + co0 + oct * 8) = v;
        }
    } else {
        float* ob = (float*)Out;
        #pragma unroll
        for (int mt = 0; mt < 4; ++mt) {
            #pragma unroll
            for (int nt = 0; nt < 4; ++nt) {
                int co = co0 + wx * 64 + nt * 16 + ln16;
                int n = n0 + wy * 64 + mt * 16 + quad * 4;
                size_t idx = (size_t)b * Cout * NP + (size_t)co * NP + n;
                f32x4 rv = *(const f32x4*)&Res[idx];
                f32x4 ov;
                #pragma unroll
                for (int r = 0; r < 4; ++r) ov[r] = rv[r] + acc[mt][nt][r];
                *(f32x4*)&ob[idx] = ov;
            }
        }
    }
}

// ---------- depthwise 3x3 in [n][c]: 4 px x 8 ch per thread ----------
template <int CH>
__global__ __launch_bounds__(256)
void dwconv3_kernel(const unsigned short* __restrict__ in,
                    const unsigned short* __restrict__ w9t,   // [9][CH]
                    unsigned short* __restrict__ out)
{
    constexpr int CHD = CH / 8;
    int gid = blockIdx.x * 256 + threadIdx.x;   // nb * NP/4 * CHD threads
    int c8 = gid % CHD;
    int rest = gid / CHD;
    int x4 = rest & 31;
    int y  = (rest >> 5) & 127;
    int b  = rest >> 12;
    int x0 = x4 * 4;
    const unsigned short* base = in + ((size_t)b * NP + y * 128 + x0) * CH + c8 * 8;
    const unsigned short* wb = w9t + c8 * 8;

    float acc[4][8];
    #pragma unroll
    for (int p = 0; p < 4; ++p)
        #pragma unroll
        for (int j = 0; j < 8; ++j) acc[p][j] = 0.f;

    #pragma unroll
    for (int dy = -1; dy <= 1; ++dy) {
        int yy = y + dy;
        if (yy < 0 || yy > 127) continue;
        float wf[3][8];
        #pragma unroll
        for (int dx = 0; dx < 3; ++dx) {
            union { uint4 q; unsigned short u[8]; } wv;
            wv.q = *(const uint4*)(wb + ((dy + 1) * 3 + dx) * CH);
            #pragma unroll
            for (int j = 0; j < 8; ++j) wf[dx][j] = b2f(wv.u[j]);
        }
        float pf[6][8];
        #pragma unroll
        for (int p = 0; p < 6; ++p) {
            int xx = x0 + p - 1;
            if (xx < 0 || xx > 127) {
                #pragma unroll
                for (int j = 0; j < 8; ++j) pf[p][j] = 0.f;
            } else {
                union { uint4 q; unsigned short u[8]; } pv;
                pv.q = *(const uint4*)(base + (ptrdiff_t)(dy * 128 + p - 1) * CH);
                #pragma unroll
                for (int j = 0; j < 8; ++j) pf[p][j] = b2f(pv.u[j]);
            }
        }
        #pragma unroll
        for (int dx = 0; dx < 3; ++dx)
            #pragma unroll
            for (int p = 0; p < 4; ++p)
                #pragma unroll
                for (int j = 0; j < 8; ++j)
                    acc[p][j] += wf[dx][j] * pf[p + dx][j];
    }
    #pragma unroll
    for (int p = 0; p < 4; ++p) {
        union { uint4 q; unsigned short u[8]; } res;
        #pragma unroll
        for (int j = 0; j < 8; ++j) res.u[j] = f2b(acc[p][j]);
        *(uint4*)(out + ((size_t)b * NP + y * 128 + x0 + p) * CH + c8 * 8) = res.q;
    }
}

// ---------- fused dw3x3 + tanh-GELU gate in [n][c]: 4 px x 8 ch ----------
__global__ __launch_bounds__(256)
void dwgelu_kernel(const unsigned short* __restrict__ hdn,   // [n][512]
                   const unsigned short* __restrict__ w9t,   // [9][512]
                   unsigned short* __restrict__ g)           // [n][256]
{
    int gid = blockIdx.x * 256 + threadIdx.x;   // nb * NP/4 * 32 threads
    int c8 = gid & 31;
    int rest = gid >> 5;
    int x4 = rest & 31;
    int y  = (rest >> 5) & 127;
    int b  = rest >> 12;
    int x0 = x4 * 4;
    const unsigned short* base = hdn + ((size_t)b * NP + y * 128 + x0) * 512 + c8 * 8;
    const unsigned short* wb = w9t + c8 * 8;

    float a1[4][8], a2[4][8];
    #pragma unroll
    for (int p = 0; p < 4; ++p)
        #pragma unroll
        for (int j = 0; j < 8; ++j) { a1[p][j] = 0.f; a2[p][j] = 0.f; }

    #pragma unroll
    for (int str = 0; str < 2; ++str) {
        int co = str * 256;
        #pragma unroll
        for (int dy = -1; dy <= 1; ++dy) {
            int yy = y + dy;
            if (yy < 0 || yy > 127) continue;
            float wf[3][8];
            #pragma unroll
            for (int dx = 0; dx < 3; ++dx) {
                union { uint4 q; unsigned short u[8]; } wv;
                wv.q = *(const uint4*)(wb + ((dy + 1) * 3 + dx) * 512 + co);
                #pragma unroll
                for (int j = 0; j < 8; ++j) wf[dx][j] = b2f(wv.u[j]);
            }
            float pf[6][8];
            #pragma unroll
            for (int p = 0; p < 6; ++p) {
                int xx = x0 + p - 1;
                if (xx < 0 || xx > 127) {
                    #pragma unroll
                    for (int j = 0; j < 8; ++j) pf[p][j] = 0.f;
                } else {
                    union { uint4 q; unsigned short u[8]; } pv;
                    pv.q = *(const uint4*)(base + (ptrdiff_t)(dy * 128 + p - 1) * 512 + co);
                    #pragma unroll
                    for (int j = 0; j < 8; ++j) pf[p][j] = b2f(pv.u[j]);
                }
            }
            #pragma unroll
            for (int dx = 0; dx < 3; ++dx)
                #pragma unroll
                for (int p = 0; p < 4; ++p)
                    #pragma unroll
                    for (int j = 0; j < 8; ++j) {
                        if (str == 0) a1[p][j] += wf[dx][j] * pf[p + dx][j];
                        else          a2[p][j] += wf[dx][j] * pf[p + dx][j];
                    }
        }
    }
    #pragma unroll
    for (int p = 0; p < 4; ++p) {
        union { uint4 q; unsigned short u[8]; } res;
        #pragma unroll
        for (int j = 0; j < 8; ++j) {
            float u = a1[p][j];
            float tt = u * (0.7978845608f + 0.0356774081f * u * u);
            float e = __expf(2.f * tt);
            float th = 1.f - 2.f / (e + 1.f);
            res.u[j] = f2b(0.5f * u * (1.f + th) * a2[p][j]);
        }
        *(uint4*)(g + ((size_t)b * NP + y * 128 + x0 + p) * 256 + c8 * 8) = res.q;
    }
}

// ---------- sum of squares per (b, ch<256) over n; atomic accumulate ----------
__global__ __launch_bounds__(256)
void sumsq_kernel(const unsigned short* __restrict__ qkv, float* __restrict__ norms2)
{
    int t = threadIdx.x;
    int c8 = t & 31, npar = t >> 5;
    int b = blockIdx.y;
    int nbase = blockIdx.x * 64 + npar * 8;
    float ps[8];
    #pragma unroll
    for (int j = 0; j < 8; ++j) ps[j] = 0.f;
    for (int i = 0; i < 8; ++i) {
        int n = nbase + i;
        union { uint4 q; unsigned short u[8]; } cv;
        cv.q = *(const uint4*)(qkv + ((size_t)b * NP + n) * 384 + c8 * 8);
        #pragma unroll
        for (int j = 0; j < 8; ++j) { float v = b2f(cv.u[j]); ps[j] += v * v; }
    }
    __shared__ float sm[8][256];
    #pragma unroll
    for (int j = 0; j < 8; ++j) sm[npar][c8 * 8 + j] = ps[j];
    __syncthreads();
    float s = 0.f;
    #pragma unroll
    for (int k = 0; k < 8; ++k) s += sm[k][t];
    atomicAdd(&norms2[b * 256 + t], s);
}

// ---------- Gram partials with in-LDS transpose: Spart[b,h,slot(32)][dq][dk] ----------
__global__ __launch_bounds__(256)
void gram_kernel(const unsigned short* __restrict__ qkv, float* __restrict__ Spart)
{
    __shared__ unsigned short Qs[16][136], Ks[16][136];
    int h = blockIdx.x, b = blockIdx.y, sp = blockIdx.z;   // sp 0..7, 2048 n each
    int t = threadIdx.x;
    int wave = t >> 6, lane = t & 63;
    int ln16 = lane & 15, quad = lane >> 4;
    int half = t & 1, nl = t >> 1;                         // 128 rows x 2 halves

    f32x4 acc = f32x4{0.f, 0.f, 0.f, 0.f};
    for (int sub = 0; sub < 16; ++sub) {
        const unsigned short* row = qkv + ((size_t)b * NP + sp * 2048 + sub * 128 + nl) * 384 + h * 16 + half * 8;
        uint4 qv = *(const uint4*)row;
        uint4 kv = *(const uint4*)(row + 128);
        __syncthreads();
        union { uint4 q; unsigned short u[8]; } qq, kk;
        qq.q = qv; kk.q = kv;
        #pragma unroll
        for (int j = 0; j < 8; ++j) {
            Qs[half * 8 + j][nl] = qq.u[j];
            Ks[half * 8 + j][nl] = kk.u[j];
        }
        __syncthreads();
        bf16x8 aq = *(const bf16x8*)&Qs[ln16][wave * 32 + quad * 8];
        bf16x8 bk = *(const bf16x8*)&Ks[ln16][wave * 32 + quad * 8];
        acc = __builtin_amdgcn_mfma_f32_16x16x32_bf16(aq, bk, acc, 0, 0, 0);
    }
    float* Sp = Spart + (((size_t)(b * NH + h) * 32) + sp * 4 + wave) * 256;
    #pragma unroll
    for (int r = 0; r < 4; ++r)
        Sp[(quad * 4 + r) * 16 + ln16] = acc[r];
}

// ---------- softmax over dk ----------
__global__ __launch_bounds__(256)
void softmax_kernel(const float* __restrict__ Spart, const float* __restrict__ norms2,
                    const unsigned short* __restrict__ temp, float* __restrict__ P)
{
    int bh = blockIdx.x;
    int b = bh >> 3, h = bh & 7;
    int t = threadIdx.x;
    int dq = t >> 4, dk = t & 15;
    float sacc = 0.f;
    const float* Sp = Spart + (size_t)bh * 32 * 256;
    #pragma unroll
    for (int j = 0; j < 32; ++j) sacc += Sp[j * 256 + t];
    float nq = fmaxf(sqrtf(norms2[b * 256 + h * 16 + dq]), 1e-12f);
    float nk = fmaxf(sqrtf(norms2[b * 256 + 128 + h * 16 + dk]), 1e-12f);
    float v = sacc / (nq * nk) * b2f(temp[h]);
    float m = v;
    #pragma unroll
    for (int o = 8; o > 0; o >>= 1) m = fmaxf(m, __shfl_xor(m, o, 16));
    float e = __expf(v - m);
    float s = e;
    #pragma unroll
    for (int o = 8; o > 0; o >>= 1) s += __shfl_xor(s, o, 16);
    P[(size_t)bh * 256 + t] = e / s;
}

// ---------- attn-V in [n][c]: block = 32 n x 8 h ----------
__global__ __launch_bounds__(256)
void attnv_kernel(const float* __restrict__ P, const unsigned short* __restrict__ qkv,
                  unsigned short* __restrict__ out)
{
    __shared__ float Ps[8][260];
    int b = blockIdx.y;
    int t = threadIdx.x;
    const float* Pg = P + (size_t)b * NH * 256;
    #pragma unroll
    for (int i = 0; i < 8; ++i) {
        int idx = t + 256 * i;
        Ps[idx >> 8][idx & 255] = Pg[idx];
    }
    __syncthreads();
    int h = t & 7, nloc = t >> 3;
    int n = blockIdx.x * 32 + nloc;
    const unsigned short* vrow = qkv + ((size_t)b * NP + n) * 384 + 256 + h * 16;
    union { uint4 q; unsigned short u[8]; } v0, v1;
    v0.q = *(const uint4*)vrow;
    v1.q = *(const uint4*)(vrow + 8);
    float vv[16];
    #pragma unroll
    for (int j = 0; j < 8; ++j) { vv[j] = b2f(v0.u[j]); vv[8 + j] = b2f(v1.u[j]); }
    union { uint4 q[2]; unsigned short u[16]; } res;
    #pragma unroll
    for (int dq = 0; dq < 16; ++dq) {
        float o = 0.f;
        #pragma unroll
        for (int e4 = 0; e4 < 4; ++e4) {
            f32x4 p4 = *(const f32x4*)&Ps[h][dq * 16 + e4 * 4];
            o += p4[0] * vv[e4 * 4] + p4[1] * vv[e4 * 4 + 1] + p4[2] * vv[e4 * 4 + 2] + p4[3] * vv[e4 * 4 + 3];
        }
        res.u[dq] = f2b(o);
    }
    unsigned short* op = out + ((size_t)b * NP + n) * C + h * 16;
    *(uint4*)op = res.q[0];
    *(uint4*)(op + 8) = res.q[1];
}

// ---------- pipeline ----------
struct Bufs {
    float* xmid;            // [c][n] fp32 trunk
    unsigned short* y;      // [n][128] bf16
    unsigned short* big;    // [n][512] bf16
    unsigned short* mid;    // [n][384] / [n][256] bf16
    float* norms2;          // nb*256
    float* Spart;           // nb*NH*32*256
    float* P;               // nb*NH*256
};

static void run_pipeline(const float* x_f32, float* out_f32,
                         const unsigned short* w, const Bufs& B, int nb, hipStream_t stream)
{
    const unsigned short* ln1_w   = w + 0;
    const unsigned short* ln1_b   = w + 128;
    const unsigned short* temp    = w + 256;
    const unsigned short* qkv_p_w = w + 272;
    const unsigned short* qkv_d_w = w + 49424;    // [9][384]
    const unsigned short* proj_w  = w + 52880;
    const unsigned short* ln2_w   = w + 69264;
    const unsigned short* ln2_b   = w + 69392;
    const unsigned short* g1_w    = w + 69520;
    const unsigned short* gd_w    = w + 135056;   // [9][512]
    const unsigned short* g2_w    = w + 139664;

    // ---- MDTA ----
    ln_kernel<<<nb * NP / 16, 256, 0, stream>>>(x_f32, ln1_w, ln1_b, B.y);
    gemm_pconv<128, 0><<<dim3(NP / 128, 3, nb), 256, 0, stream>>>(qkv_p_w, B.y, B.big, nullptr, 384);
    dwconv3_kernel<384><<<nb * (NP / 4) * 48 / 256, 256, 0, stream>>>(B.big, qkv_d_w, B.mid);
    zero_kernel<<<nb, 256, 0, stream>>>(B.norms2);
    sumsq_kernel<<<dim3(NP / 64, nb), 256, 0, stream>>>(B.mid, B.norms2);
    gram_kernel<<<dim3(NH, nb, 8), 256, 0, stream>>>(B.mid, B.Spart);
    softmax_kernel<<<nb * NH, 256, 0, stream>>>(B.Spart, B.norms2, temp, B.P);
    attnv_kernel<<<dim3(NP / 32, nb), 256, 0, stream>>>(B.P, B.mid, B.y);
    gemm_pconv<128, 1><<<dim3(NP / 128, 1, nb), 256, 0, stream>>>(proj_w, B.y, B.xmid, x_f32, 128);

    // ---- GDFN ----
    ln_kernel<<<nb * NP / 16, 256, 0, stream>>>(B.xmid, ln2_w, ln2_b, B.y);
    gemm_pconv<128, 0><<<dim3(NP / 128, 4, nb), 256, 0, stream>>>(g1_w, B.y, B.big, nullptr, 512);
    dwgelu_kernel<<<nb * (NP / 4) * 32 / 256, 256, 0, stream>>>(B.big, gd_w, B.mid);
    gemm_pconv<256, 1><<<dim3(NP / 128, 1, nb), 256, 0, stream>>>(g2_w, B.mid, out_f32, B.xmid, 128);
}

extern "C" void kernel_launch(void* const* d_in, const int* in_sizes, int n_in,
                              void* d_out, int out_size, void* d_ws, size_t ws_size,
                              hipStream_t stream)
{
    (void)in_sizes; (void)n_in; (void)out_size;
    const float* x = (const float*)d_in[0];
    char* ws = (char*)d_ws;

    size_t off = 0;
    unsigned short* wpack = (unsigned short*)(ws + off);
    off += (size_t)kWTotal * 2;
    off = (off + 255) & ~(size_t)255;
    size_t header = off;

    auto layout = [&](int nb, size_t o, Bufs& B) -> size_t {
        B.xmid = (float*)(ws + o);           o += (size_t)nb * C * NP * 4;
        B.y    = (unsigned short*)(ws + o);  o += (size_t)nb * C * NP * 2;
        B.big  = (unsigned short*)(ws + o);  o += (size_t)nb * 512 * NP * 2;
        B.mid  = (unsigned short*)(ws + o);  o += (size_t)nb * 384 * NP * 2;
        B.norms2 = (float*)(ws + o);         o += (size_t)nb * 256 * 4;
        B.Spart  = (float*)(ws + o);         o += (size_t)nb * NH * 32 * 256 * 4;
        B.P      = (float*)(ws + o);         o += (size_t)nb * NH * 256 * 4;
        return o;
    };

    Ptr11 P;
    for (int i = 0; i < 11; ++i) P.p[i] = (const float*)d_in[i + 1];
    cvt_w_kernel<<<dim3(256, 11), 256, 0, stream>>>(P, wpack);

    Bufs Bfull;
    size_t need_full = layout(4, header, Bfull);

    if (ws_size >= need_full) {
        run_pipeline(x, (float*)d_out, wpack, Bfull, 4, stream);
    } else {
        Bufs B1;
        layout(1, header, B1);
        for (int b = 0; b < 4; ++b) {
            run_pipeline(x + (size_t)b * C * NP,
                         (float*)d_out + (size_t)b * C * NP,
                         wpack, B1, 1, stream);
        }
    }
}

// Round 9
// 308.418 us; speedup vs baseline: 1.1777x; 1.1539x over previous
//
#include <hip/hip_runtime.h>
#include <cstdint>
#include <cstddef>

typedef float f32x4 __attribute__((ext_vector_type(4)));
typedef __bf16 bf16x8 __attribute__((ext_vector_type(8)));

__device__ __forceinline__ float b2f(unsigned short u) {
    union { unsigned int i; float f; } z; z.i = ((unsigned int)u) << 16; return z.f;
}
__device__ __forceinline__ unsigned short f2b(float f) {
    union { float f; unsigned int i; } z; z.f = f;
    unsigned int x = z.i;
    return (unsigned short)((x + 0x7FFFu + ((x >> 16) & 1u)) >> 16);
}

static constexpr int C = 128;
static constexpr int NP = 16384;      // H*W
static constexpr int NH = 8;

// ---------- weight pack: fp32 -> bf16 (natural layouts) ----------
struct Ptr11 { const float* p[11]; };
__constant__ int kWN[11]   = {128, 128, 8, 49152, 3456, 16384, 128, 128, 65536, 4608, 32768};
__constant__ int kWOff[11] = {0, 128, 256, 272, 49424, 52880, 69264, 69392, 69520, 135056, 139664};
static constexpr int kWTotal = 172432;

__global__ __launch_bounds__(256)
void cvt_w_kernel(Ptr11 P, unsigned short* __restrict__ dst)
{
    int seg = blockIdx.y;
    int n = kWN[seg];
    int i = blockIdx.x * 256 + threadIdx.x;
    if (i >= n) return;
    dst[kWOff[seg] + i] = f2b(P.p[seg][i]);
}

__global__ void zero_kernel(float* __restrict__ p) { p[blockIdx.x * 256 + threadIdx.x] = 0.f; }

// ---------- LayerNorm: fp32 [c][n] in -> bf16 [n][128] out (proven r7/r8) ----------
__global__ __launch_bounds__(256)
void ln_kernel(const float* __restrict__ x, const unsigned short* __restrict__ g,
               const unsigned short* __restrict__ beta, unsigned short* __restrict__ y)
{
    int t = threadIdx.x;
    int px = t & 15;
    int tg = t >> 4;
    int pglob = blockIdx.x * 16 + px;      // b*NP+n
    int b = pglob >> 14;
    int n = pglob & (NP - 1);
    const float* xb = x + (size_t)b * C * NP + n;

    float v[8]; float s = 0.f, s2 = 0.f;
    #pragma unroll
    for (int i = 0; i < 8; ++i) {
        float w = xb[(size_t)(tg * 8 + i) * NP];
        v[i] = w; s += w; s2 += w * w;
    }
    s  += __shfl_xor(s, 16, 64);  s2 += __shfl_xor(s2, 16, 64);
    s  += __shfl_xor(s, 32, 64);  s2 += __shfl_xor(s2, 32, 64);
    __shared__ float sm[2][4][16];
    if ((t & 63) < 16) { sm[0][t >> 6][px] = s; sm[1][t >> 6][px] = s2; }
    __syncthreads();
    float S  = sm[0][0][px] + sm[0][1][px] + sm[0][2][px] + sm[0][3][px];
    float S2 = sm[1][0][px] + sm[1][1][px] + sm[1][2][px] + sm[1][3][px];
    float mu = S * (1.0f / C);
    float var = S2 * (1.0f / C) - mu * mu;
    float rs = rsqrtf(fmaxf(var, 0.f) + 1e-5f);

    union { uint4 q; unsigned short u[8]; } res;
    #pragma unroll
    for (int i = 0; i < 8; ++i) {
        int c = tg * 8 + i;
        res.u[i] = f2b((v[i] - mu) * rs * b2f(g[c]) + b2f(beta[c]));
    }
    *(uint4*)(y + (size_t)pglob * C + tg * 8) = res.q;
}

// ---------- LDS-free GEMM: A=X'[n][k], B=W[co][k], both k-contig ----------
// EPI 0: Out bf16 [co][n] via LDS transpose epilogue (coalesced).
// EPI 1: Out fp32 [co][n] = Res + acc, float4 RMW (proven r8).
template <int K, int EPI>
__global__ __launch_bounds__(256)
void gemm_nk(const unsigned short* __restrict__ W,
             const unsigned short* __restrict__ X,
             void* __restrict__ Out,
             const float* __restrict__ Res,
             int Cout)
{
    const int tid = threadIdx.x;
    const int b = blockIdx.z;
    const int n0 = blockIdx.x * 128;
    const int co0 = blockIdx.y * 128;
    const int lane = tid & 63;
    const int wid = tid >> 6;
    const int ln16 = lane & 15;
    const int quad = lane >> 4;
    const int wy = wid >> 1;     // n half
    const int wx = wid & 1;      // co half
    const unsigned short* Xb = X + ((size_t)b * NP + n0) * K;

    f32x4 acc[4][4];
    #pragma unroll
    for (int i = 0; i < 4; ++i)
        #pragma unroll
        for (int j = 0; j < 4; ++j)
            acc[i][j] = f32x4{0.f, 0.f, 0.f, 0.f};

    #pragma unroll 2
    for (int k0 = 0; k0 < K; k0 += 32) {
        bf16x8 afr[4];
        #pragma unroll
        for (int mt = 0; mt < 4; ++mt) {
            int row = wy * 64 + mt * 16 + ln16;
            uint4 v = *(const uint4*)(Xb + (size_t)row * K + k0 + quad * 8);
            afr[mt] = *(bf16x8*)&v;
        }
        bf16x8 bfr[4];
        #pragma unroll
        for (int nt = 0; nt < 4; ++nt) {
            int co = co0 + wx * 64 + nt * 16 + ln16;
            uint4 v = *(const uint4*)(W + (size_t)co * K + k0 + quad * 8);
            bfr[nt] = *(bf16x8*)&v;
        }
        #pragma unroll
        for (int mt = 0; mt < 4; ++mt)
            #pragma unroll
            for (int nt = 0; nt < 4; ++nt)
                acc[mt][nt] = __builtin_amdgcn_mfma_f32_16x16x32_bf16(
                    afr[mt], bfr[nt], acc[mt][nt], 0, 0, 0);
    }

    // D: row (= pixel n) = wy*64+mt*16+quad*4+r, col (= co) = wx*64+nt*16+ln16
    if constexpr (EPI == 0) {
        __shared__ unsigned short Ts[128 * 136];   // [co_local][n_local pad 136]
        #pragma unroll
        for (int mt = 0; mt < 4; ++mt) {
            #pragma unroll
            for (int nt = 0; nt < 4; ++nt) {
                int co_l = wx * 64 + nt * 16 + ln16;
                int n_l  = wy * 64 + mt * 16 + quad * 4;
                union { uint2 d; unsigned short u[4]; } pk;
                #pragma unroll
                for (int r = 0; r < 4; ++r) pk.u[r] = f2b(acc[mt][nt][r]);
                *(uint2*)&Ts[co_l * 136 + n_l] = pk.d;
            }
        }
        __syncthreads();
        unsigned short* ob = (unsigned short*)Out;
        #pragma unroll
        for (int i = 0; i < 8; ++i) {
            int idx = tid + 256 * i;       // 0..2047
            int co_l = idx >> 4;
            int oct  = idx & 15;
            uint4 v = *(const uint4*)&Ts[co_l * 136 + oct * 8];
            *(uint4*)(ob + (size_t)b * Cout * NP + (size_t)(co0 + co_l) * NP + n0 + oct * 8) = v;
        }
    } else {
        float* ob = (float*)Out;
        #pragma unroll
        for (int mt = 0; mt < 4; ++mt) {
            #pragma unroll
            for (int nt = 0; nt < 4; ++nt) {
                int co = co0 + wx * 64 + nt * 16 + ln16;
                int n = n0 + wy * 64 + mt * 16 + quad * 4;
                size_t idx = (size_t)b * Cout * NP + (size_t)co * NP + n;
                f32x4 rv = *(const f32x4*)&Res[idx];
                f32x4 ov;
                #pragma unroll
                for (int r = 0; r < 4; ++r) ov[r] = rv[r] + acc[mt][nt][r];
                *(f32x4*)&ob[idx] = ov;
            }
        }
    }
}

// ---------- staged-B GEMM (proven v5) for g2: X [k][n], W [co][k] ----------
template <int K>
__global__ __launch_bounds__(256)
void gemm_cn(const unsigned short* __restrict__ W,
             const unsigned short* __restrict__ X,     // [b][K][NP]
             float* __restrict__ Out,                  // [b][Cout][NP] fp32
             const float* __restrict__ Res,
             int Cout)
{
    __shared__ unsigned short Bs[32][128];
    const int tid = threadIdx.x;
    const int b = blockIdx.z;
    const int n0 = blockIdx.x * 128;
    const int m0 = blockIdx.y * 128;
    const unsigned short* Xb = X + (size_t)b * K * NP;
    const int wid = tid >> 6;
    const int lane = tid & 63;
    const int ln16 = lane & 15;
    const int quad = lane >> 4;
    const int wy = wid >> 1;
    const int wx = wid & 1;

    f32x4 acc[4][4];
    #pragma unroll
    for (int i = 0; i < 4; ++i)
        #pragma unroll
        for (int j = 0; j < 4; ++j)
            acc[i][j] = f32x4{0.f, 0.f, 0.f, 0.f};

    for (int k0 = 0; k0 < K; k0 += 32) {
        #pragma unroll
        for (int r = 0; r < 2; ++r) {
            int flat = tid + r * 256;
            int kk = flat >> 4;
            int nn = (flat & 15) * 8;
            uint4 v = *(const uint4*)(Xb + (size_t)(k0 + kk) * NP + n0 + nn);
            *(uint4*)(&Bs[kk][nn]) = v;
        }
        __syncthreads();

        bf16x8 afr[4];
        #pragma unroll
        for (int mt = 0; mt < 4; ++mt) {
            int m = m0 + wy * 64 + mt * 16 + ln16;
            uint4 v = *(const uint4*)(W + (size_t)m * K + k0 + quad * 8);
            afr[mt] = *(bf16x8*)&v;
        }
        bf16x8 bfr[4];
        #pragma unroll
        for (int nt = 0; nt < 4; ++nt) {
            int n = wx * 64 + nt * 16 + ln16;
            union { bf16x8 v; unsigned short u[8]; } tmp;
            #pragma unroll
            for (int j = 0; j < 8; ++j) tmp.u[j] = Bs[quad * 8 + j][n];
            bfr[nt] = tmp.v;
        }
        #pragma unroll
        for (int mt = 0; mt < 4; ++mt)
            #pragma unroll
            for (int nt = 0; nt < 4; ++nt)
                acc[mt][nt] = __builtin_amdgcn_mfma_f32_16x16x32_bf16(
                    afr[mt], bfr[nt], acc[mt][nt], 0, 0, 0);
        __syncthreads();
    }

    #pragma unroll
    for (int mt = 0; mt < 4; ++mt) {
        #pragma unroll
        for (int nt = 0; nt < 4; ++nt) {
            int co0 = m0 + wy * 64 + mt * 16 + quad * 4;
            int n = n0 + wx * 64 + nt * 16 + ln16;
            #pragma unroll
            for (int r = 0; r < 4; ++r) {
                size_t idx = (size_t)b * Cout * NP + (size_t)(co0 + r) * NP + n;
                Out[idx] = Res[idx] + acc[mt][nt][r];
            }
        }
    }
}

// ---------- depthwise 3x3 [c][n], 8px/thread, shuffle halos + fused q/k sumsq ----------
__global__ __launch_bounds__(256)
void dwconv3_kernel(const unsigned short* __restrict__ in,
                    const unsigned short* __restrict__ w9,
                    unsigned short* __restrict__ out, int CH,
                    float* __restrict__ norms2)
{
    int t = blockIdx.x * 256 + threadIdx.x;
    int xi = (t & 15) * 8;
    int y  = (t >> 4) & 127;
    int bc = t >> 11;                 // uniform per block
    int c  = bc % CH;
    int b  = bc / CH;
    const unsigned short* base = in + (size_t)bc * NP + y * 128 + xi;

    float wr[9];
    #pragma unroll
    for (int i = 0; i < 9; ++i) wr[i] = b2f(w9[c * 9 + i]);

    uint4 rv0 = uint4{0,0,0,0}, rv1, rv2 = uint4{0,0,0,0};
    if (y > 0)   rv0 = *(const uint4*)(base - 128);
    rv1 = *(const uint4*)(base);
    if (y < 127) rv2 = *(const uint4*)(base + 128);
    uint4 rows[3] = {rv0, rv1, rv2};

    float o[8];
    #pragma unroll
    for (int j = 0; j < 8; ++j) o[j] = 0.f;

    #pragma unroll
    for (int r = 0; r < 3; ++r) {
        union { uint4 v; unsigned short u[8]; } cv; cv.v = rows[r];
        int lh = __shfl_up((int)cv.u[7], 1, 16);
        int rh = __shfl_down((int)cv.u[0], 1, 16);
        float p[10];
        p[0] = (xi > 0)   ? b2f((unsigned short)lh) : 0.f;
        p[9] = (xi < 120) ? b2f((unsigned short)rh) : 0.f;
        #pragma unroll
        for (int j = 0; j < 8; ++j) p[j + 1] = b2f(cv.u[j]);
        #pragma unroll
        for (int j = 0; j < 8; ++j)
            o[j] += wr[r * 3] * p[j] + wr[r * 3 + 1] * p[j + 1] + wr[r * 3 + 2] * p[j + 2];
    }
    union { uint4 v; unsigned short u[8]; } res;
    float ss = 0.f;
    #pragma unroll
    for (int j = 0; j < 8; ++j) { res.u[j] = f2b(o[j]); ss += o[j] * o[j]; }
    *(uint4*)(out + (size_t)bc * NP + y * 128 + xi) = res.v;

    // fused sum-of-squares for q,k channels (c < 256)
    #pragma unroll
    for (int off = 32; off > 0; off >>= 1) ss += __shfl_down(ss, off, 64);
    __shared__ float sred[4];
    if ((threadIdx.x & 63) == 0) sred[threadIdx.x >> 6] = ss;
    __syncthreads();
    if (threadIdx.x == 0 && c < 256)
        atomicAdd(&norms2[b * 256 + c], sred[0] + sred[1] + sred[2] + sred[3]);
}

// ---------- fused dw3x3 + tanh-GELU gate [c][n], 8px/thread (proven v5) ----------
__global__ __launch_bounds__(256)
void dwgelu_kernel(const unsigned short* __restrict__ hdn,
                   const unsigned short* __restrict__ w9,
                   unsigned short* __restrict__ g)
{
    int t = blockIdx.x * 256 + threadIdx.x;
    int xi = (t & 15) * 8;
    int y  = (t >> 4) & 127;
    int bc = t >> 11;
    int c  = bc & 255;
    int b  = bc >> 8;
    const unsigned short* base1 = hdn + ((size_t)b * 512 + c) * NP + y * 128 + xi;
    const unsigned short* base2 = base1 + (size_t)256 * NP;

    float w1[9], w2[9];
    #pragma unroll
    for (int i = 0; i < 9; ++i) {
        w1[i] = b2f(w9[c * 9 + i]);
        w2[i] = b2f(w9[(c + 256) * 9 + i]);
    }

    uint4 ra0 = uint4{0,0,0,0}, ra1, ra2 = uint4{0,0,0,0};
    uint4 rb0 = uint4{0,0,0,0}, rb1, rb2 = uint4{0,0,0,0};
    if (y > 0)   { ra0 = *(const uint4*)(base1 - 128); rb0 = *(const uint4*)(base2 - 128); }
    ra1 = *(const uint4*)(base1);
    rb1 = *(const uint4*)(base2);
    if (y < 127) { ra2 = *(const uint4*)(base1 + 128); rb2 = *(const uint4*)(base2 + 128); }
    uint4 rowsA[3] = {ra0, ra1, ra2};
    uint4 rowsB[3] = {rb0, rb1, rb2};

    float a1[8], a2[8];
    #pragma unroll
    for (int j = 0; j < 8; ++j) { a1[j] = 0.f; a2[j] = 0.f; }

    #pragma unroll
    for (int r = 0; r < 3; ++r) {
        union { uint4 v; unsigned short u[8]; } c1, c2;
        c1.v = rowsA[r]; c2.v = rowsB[r];
        int lh1 = __shfl_up((int)c1.u[7], 1, 16);
        int rh1 = __shfl_down((int)c1.u[0], 1, 16);
        int lh2 = __shfl_up((int)c2.u[7], 1, 16);
        int rh2 = __shfl_down((int)c2.u[0], 1, 16);
        float p1[10], p2[10];
        p1[0] = (xi > 0)   ? b2f((unsigned short)lh1) : 0.f;
        p1[9] = (xi < 120) ? b2f((unsigned short)rh1) : 0.f;
        p2[0] = (xi > 0)   ? b2f((unsigned short)lh2) : 0.f;
        p2[9] = (xi < 120) ? b2f((unsigned short)rh2) : 0.f;
        #pragma unroll
        for (int j = 0; j < 8; ++j) { p1[j + 1] = b2f(c1.u[j]); p2[j + 1] = b2f(c2.u[j]); }
        #pragma unroll
        for (int j = 0; j < 8; ++j) {
            a1[j] += w1[r * 3] * p1[j] + w1[r * 3 + 1] * p1[j + 1] + w1[r * 3 + 2] * p1[j + 2];
            a2[j] += w2[r * 3] * p2[j] + w2[r * 3 + 1] * p2[j + 1] + w2[r * 3 + 2] * p2[j + 2];
        }
    }
    union { uint4 v; unsigned short u[8]; } res;
    #pragma unroll
    for (int j = 0; j < 8; ++j) {
        float u = a1[j];
        float tt = u * (0.7978845608f + 0.0356774081f * u * u);
        float e = __expf(2.f * tt);
        float th = 1.f - 2.f / (e + 1.f);
        res.u[j] = f2b(0.5f * u * (1.f + th) * a2[j]);
    }
    *(uint4*)(g + (size_t)bc * NP + y * 128 + xi) = res.v;
}

// ---------- Gram partials direct-from-global [c][n] (proven v5) ----------
__global__ __launch_bounds__(256)
void gram_kernel(const unsigned short* __restrict__ qkv, float* __restrict__ Spart)
{
    int h = blockIdx.x, b = blockIdx.y, sp = blockIdx.z;
    int wid = threadIdx.x >> 6, lane = threadIdx.x & 63;
    int ln16 = lane & 15, quad = lane >> 4;
    int nbase = sp * 2048 + wid * 512;
    const unsigned short* qp = qkv + ((size_t)b * 384 + h * 16 + ln16) * NP;
    const unsigned short* kp = qkv + ((size_t)b * 384 + 128 + h * 16 + ln16) * NP;
    f32x4 acc = f32x4{0.f, 0.f, 0.f, 0.f};
    for (int i = 0; i < 512; i += 32) {
        int n = nbase + i + quad * 8;
        uint4 av = *(const uint4*)(qp + n);
        uint4 bv = *(const uint4*)(kp + n);
        acc = __builtin_amdgcn_mfma_f32_16x16x32_bf16(*(bf16x8*)&av, *(bf16x8*)&bv, acc, 0, 0, 0);
    }
    float* Sp = Spart + (((size_t)(b * NH + h) * 32) + sp * 4 + wid) * 256;
    #pragma unroll
    for (int r = 0; r < 4; ++r)
        Sp[(quad * 4 + r) * 16 + ln16] = acc[r];
}

// ---------- softmax over dk (norms2 + sqrt, proven r8) ----------
__global__ __launch_bounds__(256)
void softmax_kernel(const float* __restrict__ Spart, const float* __restrict__ norms2,
                    const unsigned short* __restrict__ temp, float* __restrict__ P)
{
    int bh = blockIdx.x;
    int b = bh >> 3, h = bh & 7;
    int t = threadIdx.x;
    int dq = t >> 4, dk = t & 15;
    float sacc = 0.f;
    const float* Sp = Spart + (size_t)bh * 32 * 256;
    #pragma unroll
    for (int j = 0; j < 32; ++j) sacc += Sp[j * 256 + t];
    float nq = fmaxf(sqrtf(norms2[b * 256 + h * 16 + dq]), 1e-12f);
    float nk = fmaxf(sqrtf(norms2[b * 256 + 128 + h * 16 + dk]), 1e-12f);
    float v = sacc / (nq * nk) * b2f(temp[h]);
    float m = v;
    #pragma unroll
    for (int o = 8; o > 0; o >>= 1) m = fmaxf(m, __shfl_xor(m, o, 16));
    float e = __expf(v - m);
    float s = e;
    #pragma unroll
    for (int o = 8; o > 0; o >>= 1) s += __shfl_xor(s, o, 16);
    P[(size_t)bh * 256 + t] = e / s;
}

// ---------- attn-V: v from [c][n] (v5 loop), OUT to [n][128] for LDS-free proj ----------
__global__ __launch_bounds__(256)
void attnv_kernel(const float* __restrict__ P, const unsigned short* __restrict__ qkv,
                  unsigned short* __restrict__ out)   // [b][n][128]
{
    __shared__ float Ps[256];
    int h = blockIdx.y, b = blockIdx.z;
    Ps[threadIdx.x] = P[((size_t)b * NH + h) * 256 + threadIdx.x];
    __syncthreads();
    int n0 = (blockIdx.x * 256 + threadIdx.x) * 4;
    const unsigned short* vp = qkv + ((size_t)b * 384 + 256 + h * 16) * NP + n0;
    float o[16][4];
    #pragma unroll
    for (int d = 0; d < 16; ++d)
        #pragma unroll
        for (int j = 0; j < 4; ++j) o[d][j] = 0.f;
    #pragma unroll
    for (int e = 0; e < 16; ++e) {
        union { uint2 v; unsigned short u[4]; } cv;
        cv.v = *(const uint2*)(vp + (size_t)e * NP);
        float v0 = b2f(cv.u[0]), v1 = b2f(cv.u[1]), v2 = b2f(cv.u[2]), v3 = b2f(cv.u[3]);
        #pragma unroll
        for (int d = 0; d < 16; ++d) {
            float p = Ps[d * 16 + e];
            o[d][0] += p * v0; o[d][1] += p * v1; o[d][2] += p * v2; o[d][3] += p * v3;
        }
    }
    #pragma unroll
    for (int j = 0; j < 4; ++j) {
        union { uint4 q[2]; unsigned short u[16]; } res;
        #pragma unroll
        for (int d = 0; d < 16; ++d) res.u[d] = f2b(o[d][j]);
        unsigned short* op = out + ((size_t)b * NP + n0 + j) * 128 + h * 16;
        *(uint4*)op = res.q[0];
        *(uint4*)(op + 8) = res.q[1];
    }
}

// ---------- pipeline ----------
struct Bufs {
    float* xmid;            // [c][n] fp32 trunk
    unsigned short* y;      // [n][128] bf16 (ln out / attn out)
    unsigned short* big;    // [c][n] up to 512 ch
    unsigned short* mid;    // [c][n] up to 384 ch
    float* norms2;          // nb*256
    float* Spart;           // nb*NH*32*256
    float* P;               // nb*NH*256
};

static void run_pipeline(const float* x_f32, float* out_f32,
                         const unsigned short* w, const Bufs& B, int nb, hipStream_t stream)
{
    const unsigned short* ln1_w   = w + 0;
    const unsigned short* ln1_b   = w + 128;
    const unsigned short* temp    = w + 256;
    const unsigned short* qkv_p_w = w + 272;
    const unsigned short* qkv_d_w = w + 49424;
    const unsigned short* proj_w  = w + 52880;
    const unsigned short* ln2_w   = w + 69264;
    const unsigned short* ln2_b   = w + 69392;
    const unsigned short* g1_w    = w + 69520;
    const unsigned short* gd_w    = w + 135056;
    const unsigned short* g2_w    = w + 139664;

    // ---- MDTA ----
    ln_kernel<<<nb * NP / 16, 256, 0, stream>>>(x_f32, ln1_w, ln1_b, B.y);
    gemm_nk<128, 0><<<dim3(NP / 128, 3, nb), 256, 0, stream>>>(qkv_p_w, B.y, B.big, nullptr, 384);
    zero_kernel<<<nb, 256, 0, stream>>>(B.norms2);
    dwconv3_kernel<<<nb * 384 * NP / 2048, 256, 0, stream>>>(B.big, qkv_d_w, B.mid, 384, B.norms2);
    gram_kernel<<<dim3(NH, nb, 8), 256, 0, stream>>>(B.mid, B.Spart);
    softmax_kernel<<<nb * NH, 256, 0, stream>>>(B.Spart, B.norms2, temp, B.P);
    attnv_kernel<<<dim3(NP / 1024, NH, nb), 256, 0, stream>>>(B.P, B.mid, B.y);
    gemm_nk<128, 1><<<dim3(NP / 128, 1, nb), 256, 0, stream>>>(proj_w, B.y, B.xmid, x_f32, 128);

    // ---- GDFN ----
    ln_kernel<<<nb * NP / 16, 256, 0, stream>>>(B.xmid, ln2_w, ln2_b, B.y);
    gemm_nk<128, 0><<<dim3(NP / 128, 4, nb), 256, 0, stream>>>(g1_w, B.y, B.big, nullptr, 512);
    dwgelu_kernel<<<nb * 256 * NP / 2048, 256, 0, stream>>>(B.big, gd_w, B.mid);
    gemm_cn<256><<<dim3(NP / 128, 1, nb), 256, 0, stream>>>(g2_w, B.mid, out_f32, B.xmid, 128);
}

extern "C" void kernel_launch(void* const* d_in, const int* in_sizes, int n_in,
                              void* d_out, int out_size, void* d_ws, size_t ws_size,
                              hipStream_t stream)
{
    (void)in_sizes; (void)n_in; (void)out_size;
    const float* x = (const float*)d_in[0];
    char* ws = (char*)d_ws;

    size_t off = 0;
    unsigned short* wpack = (unsigned short*)(ws + off);
    off += (size_t)kWTotal * 2;
    off = (off + 255) & ~(size_t)255;
    size_t header = off;

    auto layout = [&](int nb, size_t o, Bufs& B) -> size_t {
        B.xmid = (float*)(ws + o);           o += (size_t)nb * C * NP * 4;
        B.y    = (unsigned short*)(ws + o);  o += (size_t)nb * C * NP * 2;
        B.big  = (unsigned short*)(ws + o);  o += (size_t)nb * 512 * NP * 2;
        B.mid  = (unsigned short*)(ws + o);  o += (size_t)nb * 384 * NP * 2;
        B.norms2 = (float*)(ws + o);         o += (size_t)nb * 256 * 4;
        B.Spart  = (float*)(ws + o);         o += (size_t)nb * NH * 32 * 256 * 4;
        B.P      = (float*)(ws + o);         o += (size_t)nb * NH * 256 * 4;
        return o;
    };

    Ptr11 P;
    for (int i = 0; i < 11; ++i) P.p[i] = (const float*)d_in[i + 1];
    cvt_w_kernel<<<dim3(256, 11), 256, 0, stream>>>(P, wpack);

    Bufs Bfull;
    size_t need_full = layout(4, header, Bfull);

    if (ws_size >= need_full) {
        run_pipeline(x, (float*)d_out, wpack, Bfull, 4, stream);
    } else {
        Bufs B1;
        layout(1, header, B1);
        for (int b = 0; b < 4; ++b) {
            run_pipeline(x + (size_t)b * C * NP,
                         (float*)d_out + (size_t)b * C * NP,
                         wpack, B1, 1, stream);
        }
    }
}